// Round 10
// baseline (459.002 us; speedup 1.0000x reference)
//
#include <hip/hip_runtime.h>
#include <hip/hip_fp16.h>
#include <math.h>

#define F1 128
#define C2N 8
#define SLOPE 0.2f
#define EPSBN 1e-5f

__device__ __forceinline__ unsigned fenc(float f){
  unsigned u = __float_as_uint(f);
  return (u & 0x80000000u) ? ~u : (u | 0x80000000u);
}
__device__ __forceinline__ float fdec(unsigned u){
  return (u & 0x80000000u) ? __uint_as_float(u & 0x7FFFFFFFu) : __uint_as_float(~u);
}
__device__ __forceinline__ float2 h2f2(unsigned u){
  __half2 h = *(__half2*)&u;
  return __half22float2(h);
}

// ---- fused BatchNorm stats + dst-degree histogram (independent passes) ----
__global__ __launch_bounds__(256) void k_bn_deg(const float* __restrict__ x,
    float* __restrict__ sum, float* __restrict__ sumsq, int n,
    const int* __restrict__ ei, int* __restrict__ deg, int E){
  int bid = blockIdx.x;
  if (bid < 512){
    int f = threadIdx.x & 127;
    int half = threadIdx.x >> 7;
    float s = 0.f, ss = 0.f;
    for (int r = bid*2 + half; r < n; r += 1024){
      float v = x[(size_t)r*F1 + f];
      s += v; ss += v*v;
    }
    atomicAdd(&sum[f], s);
    atomicAdd(&sumsq[f], ss);
  } else {
    int e = (bid - 512)*256 + threadIdx.x;
    if (e < E) atomicAdd(&deg[ei[E + e]], 1);
  }
}

__global__ __launch_bounds__(128) void k_bn_final(const float* __restrict__ sum,
    const float* __restrict__ sumsq, const float* __restrict__ gamma,
    const float* __restrict__ beta, float* __restrict__ ab, int n){
  int f = threadIdx.x;
  float inv_n = 1.f / (float)n;
  float mean = sum[f] * inv_n;
  float var  = sumsq[f] * inv_n - mean*mean;
  float inv  = rsqrtf(var + EPSBN);
  float a = inv * gamma[f];
  ab[f]      = a;
  ab[F1 + f] = beta[f] - mean*a;
}

// ---- normalize + x@W1 (128x128) + al1/ar1 + fused almax1; h1 fp16 ----
__global__ __launch_bounds__(128) void k_gemm1(const float* __restrict__ x,
    const float* __restrict__ ab, const float* __restrict__ W1,
    const float* __restrict__ asrc, const float* __restrict__ adst,
    __half* __restrict__ h1, float* __restrict__ al, float* __restrict__ ar,
    unsigned* __restrict__ almax, int n){
  const int j  = threadIdx.x;
  const int r0 = blockIdx.x * 8;
  __shared__ float xs[8][F1];
  float A = ab[j], B = ab[F1 + j];
  int nr = n - r0; if (nr > 8) nr = 8;
  for (int rr = 0; rr < nr; ++rr)
    xs[rr][j] = x[(size_t)(r0+rr)*F1 + j] * A + B;
  __syncthreads();
  float acc[8] = {0,0,0,0,0,0,0,0};
  for (int k = 0; k < F1; ++k){
    float w = W1[k*F1 + j];
    #pragma unroll
    for (int rr = 0; rr < 8; ++rr) acc[rr] += xs[rr][k] * w;
  }
  float as = asrc[j], ad = adst[j];
  float mxs = -1e30f;
  for (int rr = 0; rr < nr; ++rr){
    float hv = acc[rr];
    h1[(size_t)(r0+rr)*F1 + j] = __float2half(hv);
    float vs = hv*as, vd = hv*ad;
    #pragma unroll
    for (int mk = 1; mk < 32; mk <<= 1){
      vs += __shfl_xor(vs, mk);
      vd += __shfl_xor(vd, mk);
    }
    if ((j & 31) == 0){
      al[(r0+rr)*4 + (j>>5)] = vs;
      ar[(r0+rr)*4 + (j>>5)] = vd;
      mxs = fmaxf(mxs, vs);
    }
  }
  if ((j & 31) == 0) atomicMax(&almax[j>>5], fenc(mxs));
}

// ---- global column max (layer 2: H=1) ----
__global__ __launch_bounds__(256) void k_colmax(const float* __restrict__ v,
    unsigned* __restrict__ out, int total, int H){
  int tid = blockIdx.x*256 + threadIdx.x;
  int stride = gridDim.x*256;
  float mx = -1e30f;
  for (int i = tid; i < total; i += stride)
    mx = fmaxf(mx, v[i]);
  for (int m = H; m < 64; m <<= 1)
    mx = fmaxf(mx, __shfl_xor(mx, m));
  int lane = threadIdx.x & 63;
  if (lane < H) atomicMax(&out[lane], fenc(mx));
}

// ---- scan A: degrees+1 (self-loop), local exclusive scan + block sum ----
__global__ __launch_bounds__(256) void k_scan_a(const int* __restrict__ deg,
    int* __restrict__ rowptr, int* __restrict__ bsum, int n){
  int t = threadIdx.x;
  int base = blockIdx.x*1024 + t*4;
  int4 v = {0,0,0,0};
  if (base + 3 < n){
    v = *(const int4*)&deg[base];
    v.x += 1; v.y += 1; v.z += 1; v.w += 1;
  } else {
    if (base   < n) v.x = deg[base]   + 1;
    if (base+1 < n) v.y = deg[base+1] + 1;
    if (base+2 < n) v.z = deg[base+2] + 1;
    if (base+3 < n) v.w = deg[base+3] + 1;
  }
  int s = v.x + v.y + v.z + v.w;
  __shared__ int ls[256];
  ls[t] = s; __syncthreads();
  for (int off = 1; off < 256; off <<= 1){
    int u = (t >= off) ? ls[t-off] : 0;
    __syncthreads();
    ls[t] += u;
    __syncthreads();
  }
  int ex = ls[t] - s;
  if (t == 255) bsum[blockIdx.x] = ls[255];
  int4 w;
  w.x = ex;
  w.y = ex + v.x;
  w.z = w.y + v.y;
  w.w = w.z + v.z;
  if (base + 3 < n) *(int4*)&rowptr[base] = w;
  else {
    if (base   < n) rowptr[base]   = w.x;
    if (base+1 < n) rowptr[base+1] = w.y;
    if (base+2 < n) rowptr[base+2] = w.z;
    if (base+3 < n) rowptr[base+3] = w.w;
  }
}

// ---- scan C: add block offsets, mirror cursor, write rowptr[n] ----
__global__ __launch_bounds__(256) void k_scan_c(int* __restrict__ rowptr,
    int* __restrict__ cursor, const int* __restrict__ bsum, int n){
  int t = threadIdx.x;
  __shared__ int s_boff;
  if (t < 64){
    int b = blockIdx.x;
    int val = 0;
    for (int i = t; i < b; i += 64) val += bsum[i];
    #pragma unroll
    for (int m = 1; m < 64; m <<= 1) val += __shfl_xor(val, m);
    if (t == 0) s_boff = val;
  }
  __syncthreads();
  int boff = s_boff;
  if (t == 0 && blockIdx.x == gridDim.x - 1)
    rowptr[n] = boff + bsum[blockIdx.x];
  int base = blockIdx.x*1024 + t*4;
  if (base + 3 < n){
    int4 v = *(int4*)&rowptr[base];
    v.x += boff; v.y += boff; v.z += boff; v.w += boff;
    *(int4*)&rowptr[base] = v;
    *(int4*)&cursor[base] = v;
  } else {
    for (int k = 0; k < 4; ++k)
      if (base + k < n){
        int v = rowptr[base+k] + boff;
        rowptr[base+k] = v; cursor[base+k] = v;
      }
  }
}

// ---- CSR fill: one 8B packed (src,dst) store per edge ----
__global__ __launch_bounds__(256) void k_fill(const int* __restrict__ ei,
    int* __restrict__ cursor, int2* __restrict__ csr_sd, int E, int Etot){
  int e = blockIdx.x*blockDim.x + threadIdx.x;
  if (e >= Etot) return;
  int s = (e < E) ? ei[e]     : (e - E);
  int d = (e < E) ? ei[E + e] : (e - E);
  int pos = atomicAdd(&cursor[d], 1);
  csr_sd[pos] = make_int2(s, d);
}

// ---- layer-1 GAT + fused x1@W2: wave/node; lane = edge-slot(4) x slice(16) ----
__global__ __launch_bounds__(256) void k_gat1(const int* __restrict__ rowptr,
    const int2* __restrict__ csr_sd, const float* __restrict__ al,
    const float* __restrict__ ar, const unsigned* __restrict__ almax,
    const __half* __restrict__ h1, const float* __restrict__ b1,
    const float* __restrict__ W2, const float* __restrict__ as2,
    const float* __restrict__ ad2, float* __restrict__ h2,
    float* __restrict__ al2, float* __restrict__ ar2, int n){
  __shared__ float w2s[F1*9];
  for (int idx = threadIdx.x; idx < F1*C2N; idx += 256)
    w2s[(idx>>3)*9 + (idx&7)] = W2[idx];
  __syncthreads();
  int node = blockIdx.x*4 + (threadIdx.x >> 6);
  if (node >= n) return;
  int lane = threadIdx.x & 63;
  int es = lane >> 4;          // edge slot 0..3
  int fs = lane & 15;          // 8-fp16 feature slice
  int h  = fs >> 2;            // head
  int f0 = fs << 3;            // feature offset
  int beg = rowptr[node], end = rowptr[node+1];
  float ard = ar[node*4 + h];
  float ub = fdec(almax[h]) + ard;
  ub = ub > 0.f ? ub : SLOPE*ub;
  float a0=0.f,a1=0.f,a2=0.f,a3=0.f,a4=0.f,a5=0.f,a6=0.f,a7=0.f,den=0.f;
  for (int c = beg; c < end; c += 4){
    int idx = c + es;
    bool ok = idx < end;
    int s = csr_sd[ok ? idx : end-1].x;
    float alv = al[s*4 + h];
    float v = alv + ard; v = v > 0.f ? v : SLOPE*v;
    float wv = __expf(v - ub);
    wv = ok ? wv : 0.f;
    den += wv;
    uint4 hv = *(const uint4*)&h1[((size_t)s<<7) + f0];
    float2 p0 = h2f2(hv.x), p1 = h2f2(hv.y), p2 = h2f2(hv.z), p3 = h2f2(hv.w);
    a0 += wv*p0.x; a1 += wv*p0.y; a2 += wv*p1.x; a3 += wv*p1.y;
    a4 += wv*p2.x; a5 += wv*p2.y; a6 += wv*p3.x; a7 += wv*p3.y;
  }
  // reduce over the 4 edge-slot groups (lane bits 4,5) -> all lanes get sums
  #define RED2(X) { X += __shfl_xor(X,16); X += __shfl_xor(X,32); }
  RED2(a0) RED2(a1) RED2(a2) RED2(a3) RED2(a4) RED2(a5) RED2(a6) RED2(a7) RED2(den)
  #undef RED2
  // x1 row (f32, in-register), ELU
  float inv = 1.f / (den + 1e-16f);
  float4 bA = *(const float4*)&b1[f0];
  float4 bB = *(const float4*)&b1[f0+4];
  float o0 = a0*inv + bA.x, o1 = a1*inv + bA.y;
  float o2 = a2*inv + bA.z, o3 = a3*inv + bA.w;
  float o4 = a4*inv + bB.x, o5 = a5*inv + bB.y;
  float o6 = a6*inv + bB.z, o7 = a7*inv + bB.w;
  o0 = o0 > 0.f ? o0 : expm1f(o0);
  o1 = o1 > 0.f ? o1 : expm1f(o1);
  o2 = o2 > 0.f ? o2 : expm1f(o2);
  o3 = o3 > 0.f ? o3 : expm1f(o3);
  o4 = o4 > 0.f ? o4 : expm1f(o4);
  o5 = o5 > 0.f ? o5 : expm1f(o5);
  o6 = o6 > 0.f ? o6 : expm1f(o6);
  o7 = o7 > 0.f ? o7 : expm1f(o7);
  // fused gemm2: partial h2[j] from this lane's 8 k-values
  float g0=0.f,g1=0.f,g2=0.f,g3=0.f,g4=0.f,g5=0.f,g6=0.f,g7=0.f;
  const float* wp = w2s + (fs<<3)*9;
  #define GK(OV, KK) { const float* w = wp + (KK)*9; \
    g0 += OV*w[0]; g1 += OV*w[1]; g2 += OV*w[2]; g3 += OV*w[3]; \
    g4 += OV*w[4]; g5 += OV*w[5]; g6 += OV*w[6]; g7 += OV*w[7]; }
  GK(o0,0) GK(o1,1) GK(o2,2) GK(o3,3) GK(o4,4) GK(o5,5) GK(o6,6) GK(o7,7)
  #undef GK
  // reduce over the 16 slices (lane bits 0..3)
  #define RED4(X) { X += __shfl_xor(X,1); X += __shfl_xor(X,2); \
                    X += __shfl_xor(X,4); X += __shfl_xor(X,8); }
  RED4(g0) RED4(g1) RED4(g2) RED4(g3) RED4(g4) RED4(g5) RED4(g6) RED4(g7)
  #undef RED4
  if (lane == 0){
    float4 wA = {g0,g1,g2,g3}, wB = {g4,g5,g6,g7};
    *(float4*)&h2[((size_t)node<<3)]     = wA;
    *(float4*)&h2[((size_t)node<<3) + 4] = wB;
    float4 sA = *(const float4*)as2, sB = *(const float4*)(as2+4);
    float4 dA = *(const float4*)ad2, dB = *(const float4*)(ad2+4);
    al2[node] = g0*sA.x+g1*sA.y+g2*sA.z+g3*sA.w+g4*sB.x+g5*sB.y+g6*sB.z+g7*sB.w;
    ar2[node] = g0*dA.x+g1*dA.y+g2*dA.z+g3*dA.w+g4*dB.x+g5*dB.y+g6*dB.z+g7*dB.w;
  }
}

// ---- layer-2 GAT, edge-parallel: lane = one CSR edge; segmented wave scan ----
__global__ __launch_bounds__(256) void k_gat2e(const int2* __restrict__ csr_sd,
    const float* __restrict__ al, const float* __restrict__ ar,
    const unsigned* __restrict__ almax, const float* __restrict__ h2,
    float* __restrict__ nacc, float* __restrict__ nden, int Etot){
  int e = blockIdx.x*256 + threadIdx.x;
  int lane = threadIdx.x & 63;
  bool ok = e < Etot;
  int2 sd = ok ? csr_sd[e] : make_int2(0, -1);
  int s = sd.x, d = sd.y;
  float w = 0.f;
  if (ok){
    float ardv = ar[d];
    float v = al[s] + ardv; v = v > 0.f ? v : SLOPE*v;
    float ub = fdec(almax[0]) + ardv; ub = ub > 0.f ? ub : SLOPE*ub;
    w = __expf(v - ub);
  }
  float4 ha = {0,0,0,0}, hb = {0,0,0,0};
  if (ok){
    ha = *(const float4*)&h2[((size_t)s<<3)];
    hb = *(const float4*)&h2[((size_t)s<<3) + 4];
  }
  float a0 = w*ha.x, a1 = w*ha.y, a2 = w*ha.z, a3 = w*ha.w;
  float a4 = w*hb.x, a5 = w*hb.y, a6 = w*hb.z, a7 = w*hb.w;
  float den = w;
  #pragma unroll
  for (int off = 1; off < 64; off <<= 1){
    int du = __shfl_up(d, off);
    bool add = (lane >= off) && (du == d);
    float t;
    t = __shfl_up(a0, off); if (add) a0 += t;
    t = __shfl_up(a1, off); if (add) a1 += t;
    t = __shfl_up(a2, off); if (add) a2 += t;
    t = __shfl_up(a3, off); if (add) a3 += t;
    t = __shfl_up(a4, off); if (add) a4 += t;
    t = __shfl_up(a5, off); if (add) a5 += t;
    t = __shfl_up(a6, off); if (add) a6 += t;
    t = __shfl_up(a7, off); if (add) a7 += t;
    t = __shfl_up(den, off); if (add) den += t;
  }
  int dn = __shfl_down(d, 1);
  bool tail = (lane == 63) || (dn != d);
  if (tail && d >= 0){
    float* np = nacc + ((size_t)d<<3);
    atomicAdd(np+0, a0); atomicAdd(np+1, a1);
    atomicAdd(np+2, a2); atomicAdd(np+3, a3);
    atomicAdd(np+4, a4); atomicAdd(np+5, a5);
    atomicAdd(np+6, a6); atomicAdd(np+7, a7);
    atomicAdd(&nden[d], den);
  }
}

// ---- finalize layer 2 + pool scatter ----
__global__ __launch_bounds__(256) void k_fin2(const float* __restrict__ nacc,
    const float* __restrict__ nden, const float* __restrict__ b2,
    const int* __restrict__ batch, float* __restrict__ pooled,
    float* __restrict__ cnt, int n){
  int t = blockIdx.x*256 + threadIdx.x;
  int node = t >> 3, j = t & 7;
  if (node >= n) return;
  float o = nacc[t] / (nden[node] + 1e-16f) + b2[j];
  int g = batch[node];
  atomicAdd(&pooled[g*C2N + j], o);
  if (j == 0) atomicAdd(&cnt[g], 1.f);
}

// ---- mean + log_softmax ----
__global__ __launch_bounds__(256) void k_final(const float* __restrict__ pooled,
    const float* __restrict__ cnt, float* __restrict__ out, int G){
  int g = blockIdx.x*blockDim.x + threadIdx.x;
  if (g >= G) return;
  float c = cnt[g]; c = c > 1.f ? c : 1.f;
  float p[8]; float mx = -1e30f;
  #pragma unroll
  for (int j = 0; j < 8; ++j){ p[j] = pooled[g*8+j] / c; mx = fmaxf(mx, p[j]); }
  float s = 0.f;
  #pragma unroll
  for (int j = 0; j < 8; ++j) s += expf(p[j]-mx);
  float lse = mx + logf(s);
  #pragma unroll
  for (int j = 0; j < 8; ++j) out[g*8+j] = p[j] - lse;
}

extern "C" void kernel_launch(void* const* d_in, const int* in_sizes, int n_in,
                              void* d_out, int out_size, void* d_ws, size_t ws_size,
                              hipStream_t stream){
  const float* x    = (const float*)d_in[0];
  const float* gam  = (const float*)d_in[1];
  const float* bet  = (const float*)d_in[2];
  const float* W1   = (const float*)d_in[3];
  const float* as1  = (const float*)d_in[4];
  const float* ad1  = (const float*)d_in[5];
  const float* b1   = (const float*)d_in[6];
  const float* W2   = (const float*)d_in[7];
  const float* as2  = (const float*)d_in[8];
  const float* ad2  = (const float*)d_in[9];
  const float* b2   = (const float*)d_in[10];
  const int*   ei   = (const int*)d_in[11];
  const int*   batch= (const int*)d_in[12];

  int N = in_sizes[0] / F1;
  int E = in_sizes[11] / 2;
  int G = out_size / C2N;
  int Etot = E + N;
  int nb = (N + 1023) / 1024;

  char* base = (char*)d_ws;
  auto alloc = [&](size_t bytes)->char*{
    char* p = base; base += (bytes + 15) & ~15ull; return p;
  };

  // ---- region A: zeroed every launch ----
  char* A0 = base;
  float*    sum     = (float*)alloc(128*4);
  float*    sumsq   = (float*)alloc(128*4);
  int*      deg     = (int*)alloc((size_t)N*4);
  float*    pooled  = (float*)alloc((size_t)G*C2N*4);
  float*    cnt     = (float*)alloc((size_t)G*4);
  unsigned* almax1u = (unsigned*)alloc(16);
  unsigned* almax2u = (unsigned*)alloc(16);
  float*    nacc    = (float*)alloc((size_t)N*C2N*4);
  float*    nden    = (float*)alloc((size_t)N*4);
  size_t Abytes = (size_t)(base - A0);
  // ---- rest ----
  int2*    csr_sd  = (int2*)alloc((size_t)Etot*8);
  float*   ab      = (float*)alloc(256*4);
  int*     rowptr  = (int*)alloc(((size_t)N+4)*4);
  int*     cursor  = (int*)alloc((size_t)N*4);
  int*     bsum    = (int*)alloc((size_t)nb*4);
  __half*  h1      = (__half*)alloc((size_t)N*F1*2);
  float*   al1     = (float*)alloc((size_t)N*4*4);
  float*   ar1     = (float*)alloc((size_t)N*4*4);
  float*   h2      = (float*)alloc((size_t)N*C2N*4);
  float*   al2     = (float*)alloc((size_t)N*4);
  float*   ar2     = (float*)alloc((size_t)N*4);

  hipMemsetAsync(A0, 0, Abytes, stream);

  k_bn_deg<<<512 + (E + 255)/256, 256, 0, stream>>>(x, sum, sumsq, N, ei, deg, E);
  k_bn_final<<<1, 128, 0, stream>>>(sum, sumsq, gam, bet, ab, N);
  k_scan_a<<<nb, 256, 0, stream>>>(deg, rowptr, bsum, N);
  k_scan_c<<<nb, 256, 0, stream>>>(rowptr, cursor, bsum, N);
  k_fill<<<(Etot + 255)/256, 256, 0, stream>>>(ei, cursor, csr_sd, E, Etot);
  k_gemm1<<<(N + 7)/8, 128, 0, stream>>>(x, ab, W1, as1, ad1, h1, al1, ar1, almax1u, N);
  k_gat1<<<(N + 3)/4, 256, 0, stream>>>(rowptr, csr_sd, al1, ar1, almax1u, h1, b1,
                                        W2, as2, ad2, h2, al2, ar2, N);
  k_colmax<<<64, 256, 0, stream>>>(al2, almax2u, N, 1);
  k_gat2e<<<(Etot + 255)/256, 256, 0, stream>>>(csr_sd, al2, ar2, almax2u, h2, nacc, nden, Etot);
  k_fin2<<<((N*C2N) + 255)/256, 256, 0, stream>>>(nacc, nden, b2, batch, pooled, cnt, N);
  k_final<<<(G + 255)/256, 256, 0, stream>>>(pooled, cnt, (float*)d_out, G);
}

// Round 11
// 350.820 us; speedup vs baseline: 1.3084x; 1.3084x over previous
//
#include <hip/hip_runtime.h>
#include <hip/hip_fp16.h>
#include <math.h>

#define F1 128
#define C2N 8
#define SLOPE 0.2f
#define EPSBN 1e-5f

__device__ __forceinline__ unsigned fenc(float f){
  unsigned u = __float_as_uint(f);
  return (u & 0x80000000u) ? ~u : (u | 0x80000000u);
}
__device__ __forceinline__ float fdec(unsigned u){
  return (u & 0x80000000u) ? __uint_as_float(u & 0x7FFFFFFFu) : __uint_as_float(~u);
}
__device__ __forceinline__ float2 h2f2(unsigned u){
  __half2 h = *(__half2*)&u;
  return __half22float2(h);
}

// ---- fused BatchNorm stats + dst-degree histogram (independent passes) ----
__global__ __launch_bounds__(256) void k_bn_deg(const float* __restrict__ x,
    float* __restrict__ sum, float* __restrict__ sumsq, int n,
    const int* __restrict__ ei, int* __restrict__ deg, int E){
  int bid = blockIdx.x;
  if (bid < 512){
    int f = threadIdx.x & 127;
    int half = threadIdx.x >> 7;
    float s = 0.f, ss = 0.f;
    for (int r = bid*2 + half; r < n; r += 1024){
      float v = x[(size_t)r*F1 + f];
      s += v; ss += v*v;
    }
    atomicAdd(&sum[f], s);
    atomicAdd(&sumsq[f], ss);
  } else {
    int e = (bid - 512)*256 + threadIdx.x;
    if (e < E) atomicAdd(&deg[ei[E + e]], 1);
  }
}

__global__ __launch_bounds__(128) void k_bn_final(const float* __restrict__ sum,
    const float* __restrict__ sumsq, const float* __restrict__ gamma,
    const float* __restrict__ beta, float* __restrict__ ab, int n){
  int f = threadIdx.x;
  float inv_n = 1.f / (float)n;
  float mean = sum[f] * inv_n;
  float var  = sumsq[f] * inv_n - mean*mean;
  float inv  = rsqrtf(var + EPSBN);
  float a = inv * gamma[f];
  ab[f]      = a;
  ab[F1 + f] = beta[f] - mean*a;
}

// ---- normalize + x@W1 (128x128) + al1/ar1; h1 fp16 (no atomics) ----
__global__ __launch_bounds__(128) void k_gemm1(const float* __restrict__ x,
    const float* __restrict__ ab, const float* __restrict__ W1,
    const float* __restrict__ asrc, const float* __restrict__ adst,
    __half* __restrict__ h1, float* __restrict__ al, float* __restrict__ ar, int n){
  const int j  = threadIdx.x;
  const int r0 = blockIdx.x * 8;
  __shared__ float xs[8][F1];
  float A = ab[j], B = ab[F1 + j];
  int nr = n - r0; if (nr > 8) nr = 8;
  for (int rr = 0; rr < nr; ++rr)
    xs[rr][j] = x[(size_t)(r0+rr)*F1 + j] * A + B;
  __syncthreads();
  float acc[8] = {0,0,0,0,0,0,0,0};
  for (int k = 0; k < F1; ++k){
    float w = W1[k*F1 + j];
    #pragma unroll
    for (int rr = 0; rr < 8; ++rr) acc[rr] += xs[rr][k] * w;
  }
  float as = asrc[j], ad = adst[j];
  for (int rr = 0; rr < nr; ++rr){
    float hv = acc[rr];
    h1[(size_t)(r0+rr)*F1 + j] = __float2half(hv);
    float vs = hv*as, vd = hv*ad;
    #pragma unroll
    for (int mk = 1; mk < 32; mk <<= 1){
      vs += __shfl_xor(vs, mk);
      vd += __shfl_xor(vd, mk);
    }
    if ((j & 31) == 0){
      al[(r0+rr)*4 + (j>>5)] = vs;
      ar[(r0+rr)*4 + (j>>5)] = vd;
    }
  }
}

// ---- global column max of v[total] with h = i & (H-1), H power of 2 ----
__global__ __launch_bounds__(256) void k_colmax(const float* __restrict__ v,
    unsigned* __restrict__ out, int total, int H){
  int tid = blockIdx.x*256 + threadIdx.x;
  int stride = gridDim.x*256;
  float mx = -1e30f;
  for (int i = tid; i < total; i += stride)
    mx = fmaxf(mx, v[i]);
  for (int m = H; m < 64; m <<= 1)
    mx = fmaxf(mx, __shfl_xor(mx, m));
  int lane = threadIdx.x & 63;
  if (lane < H) atomicMax(&out[lane], fenc(mx));
}

// ---- scan A: degrees+1 (self-loop), local exclusive scan + block sum ----
__global__ __launch_bounds__(256) void k_scan_a(const int* __restrict__ deg,
    int* __restrict__ rowptr, int* __restrict__ bsum, int n){
  int t = threadIdx.x;
  int base = blockIdx.x*1024 + t*4;
  int4 v = {0,0,0,0};
  if (base + 3 < n){
    v = *(const int4*)&deg[base];
    v.x += 1; v.y += 1; v.z += 1; v.w += 1;
  } else {
    if (base   < n) v.x = deg[base]   + 1;
    if (base+1 < n) v.y = deg[base+1] + 1;
    if (base+2 < n) v.z = deg[base+2] + 1;
    if (base+3 < n) v.w = deg[base+3] + 1;
  }
  int s = v.x + v.y + v.z + v.w;
  __shared__ int ls[256];
  ls[t] = s; __syncthreads();
  for (int off = 1; off < 256; off <<= 1){
    int u = (t >= off) ? ls[t-off] : 0;
    __syncthreads();
    ls[t] += u;
    __syncthreads();
  }
  int ex = ls[t] - s;
  if (t == 255) bsum[blockIdx.x] = ls[255];
  int4 w;
  w.x = ex;
  w.y = ex + v.x;
  w.z = w.y + v.y;
  w.w = w.z + v.z;
  if (base + 3 < n) *(int4*)&rowptr[base] = w;
  else {
    if (base   < n) rowptr[base]   = w.x;
    if (base+1 < n) rowptr[base+1] = w.y;
    if (base+2 < n) rowptr[base+2] = w.z;
    if (base+3 < n) rowptr[base+3] = w.w;
  }
}

// ---- scan C: add block offsets, mirror cursor, write rowptr[n] ----
__global__ __launch_bounds__(256) void k_scan_c(int* __restrict__ rowptr,
    int* __restrict__ cursor, const int* __restrict__ bsum, int n){
  int t = threadIdx.x;
  __shared__ int s_boff;
  if (t < 64){
    int b = blockIdx.x;
    int val = 0;
    for (int i = t; i < b; i += 64) val += bsum[i];
    #pragma unroll
    for (int m = 1; m < 64; m <<= 1) val += __shfl_xor(val, m);
    if (t == 0) s_boff = val;
  }
  __syncthreads();
  int boff = s_boff;
  if (t == 0 && blockIdx.x == gridDim.x - 1)
    rowptr[n] = boff + bsum[blockIdx.x];
  int base = blockIdx.x*1024 + t*4;
  if (base + 3 < n){
    int4 v = *(int4*)&rowptr[base];
    v.x += boff; v.y += boff; v.z += boff; v.w += boff;
    *(int4*)&rowptr[base] = v;
    *(int4*)&cursor[base] = v;
  } else {
    for (int k = 0; k < 4; ++k)
      if (base + k < n){
        int v = rowptr[base+k] + boff;
        rowptr[base+k] = v; cursor[base+k] = v;
      }
  }
}

// ---- CSR fill: one 8B packed (src,dst) store per edge ----
__global__ __launch_bounds__(256) void k_fill(const int* __restrict__ ei,
    int* __restrict__ cursor, int2* __restrict__ csr_sd, int E, int Etot){
  int e = blockIdx.x*blockDim.x + threadIdx.x;
  if (e >= Etot) return;
  int s = (e < E) ? ei[e]     : (e - E);
  int d = (e < E) ? ei[E + e] : (e - E);
  int pos = atomicAdd(&cursor[d], 1);
  csr_sd[pos] = make_int2(s, d);
}

// ---- layer-1 GAT + fused x1@W2: wave/node; lane = edge-slot(4) x slice(16) ----
__global__ __launch_bounds__(256) void k_gat1(const int* __restrict__ rowptr,
    const int2* __restrict__ csr_sd, const float* __restrict__ al,
    const float* __restrict__ ar, const unsigned* __restrict__ almax,
    const __half* __restrict__ h1, const float* __restrict__ b1,
    const float* __restrict__ W2, const float* __restrict__ as2,
    const float* __restrict__ ad2, float* __restrict__ h2,
    float* __restrict__ al2, float* __restrict__ ar2, int n){
  __shared__ float w2s[F1*9];
  for (int idx = threadIdx.x; idx < F1*C2N; idx += 256)
    w2s[(idx>>3)*9 + (idx&7)] = W2[idx];
  __syncthreads();
  int node = blockIdx.x*4 + (threadIdx.x >> 6);
  if (node >= n) return;
  int lane = threadIdx.x & 63;
  int es = lane >> 4;          // edge slot 0..3
  int fs = lane & 15;          // 8-fp16 feature slice
  int h  = fs >> 2;            // head
  int f0 = fs << 3;            // feature offset
  int beg = rowptr[node], end = rowptr[node+1];
  float ard = ar[node*4 + h];
  float ub = fdec(almax[h]) + ard;
  ub = ub > 0.f ? ub : SLOPE*ub;
  float a0=0.f,a1=0.f,a2=0.f,a3=0.f,a4=0.f,a5=0.f,a6=0.f,a7=0.f,den=0.f;
  for (int c = beg; c < end; c += 4){
    int idx = c + es;
    bool ok = idx < end;
    int s = csr_sd[ok ? idx : end-1].x;
    float alv = al[s*4 + h];
    float v = alv + ard; v = v > 0.f ? v : SLOPE*v;
    float wv = __expf(v - ub);
    wv = ok ? wv : 0.f;
    den += wv;
    uint4 hv = *(const uint4*)&h1[((size_t)s<<7) + f0];
    float2 p0 = h2f2(hv.x), p1 = h2f2(hv.y), p2 = h2f2(hv.z), p3 = h2f2(hv.w);
    a0 += wv*p0.x; a1 += wv*p0.y; a2 += wv*p1.x; a3 += wv*p1.y;
    a4 += wv*p2.x; a5 += wv*p2.y; a6 += wv*p3.x; a7 += wv*p3.y;
  }
  // reduce over the 4 edge-slot groups (lane bits 4,5) -> all lanes get sums
  #define RED2(X) { X += __shfl_xor(X,16); X += __shfl_xor(X,32); }
  RED2(a0) RED2(a1) RED2(a2) RED2(a3) RED2(a4) RED2(a5) RED2(a6) RED2(a7) RED2(den)
  #undef RED2
  // x1 row (f32, in-register), ELU
  float inv = 1.f / (den + 1e-16f);
  float4 bA = *(const float4*)&b1[f0];
  float4 bB = *(const float4*)&b1[f0+4];
  float o0 = a0*inv + bA.x, o1 = a1*inv + bA.y;
  float o2 = a2*inv + bA.z, o3 = a3*inv + bA.w;
  float o4 = a4*inv + bB.x, o5 = a5*inv + bB.y;
  float o6 = a6*inv + bB.z, o7 = a7*inv + bB.w;
  o0 = o0 > 0.f ? o0 : expm1f(o0);
  o1 = o1 > 0.f ? o1 : expm1f(o1);
  o2 = o2 > 0.f ? o2 : expm1f(o2);
  o3 = o3 > 0.f ? o3 : expm1f(o3);
  o4 = o4 > 0.f ? o4 : expm1f(o4);
  o5 = o5 > 0.f ? o5 : expm1f(o5);
  o6 = o6 > 0.f ? o6 : expm1f(o6);
  o7 = o7 > 0.f ? o7 : expm1f(o7);
  // fused gemm2: partial h2[j] from this lane's 8 k-values
  float g0=0.f,g1=0.f,g2=0.f,g3=0.f,g4=0.f,g5=0.f,g6=0.f,g7=0.f;
  const float* wp = w2s + (fs<<3)*9;
  #define GK(OV, KK) { const float* w = wp + (KK)*9; \
    g0 += OV*w[0]; g1 += OV*w[1]; g2 += OV*w[2]; g3 += OV*w[3]; \
    g4 += OV*w[4]; g5 += OV*w[5]; g6 += OV*w[6]; g7 += OV*w[7]; }
  GK(o0,0) GK(o1,1) GK(o2,2) GK(o3,3) GK(o4,4) GK(o5,5) GK(o6,6) GK(o7,7)
  #undef GK
  // reduce over the 16 slices (lane bits 0..3)
  #define RED4(X) { X += __shfl_xor(X,1); X += __shfl_xor(X,2); \
                    X += __shfl_xor(X,4); X += __shfl_xor(X,8); }
  RED4(g0) RED4(g1) RED4(g2) RED4(g3) RED4(g4) RED4(g5) RED4(g6) RED4(g7)
  #undef RED4
  if (lane == 0){
    float4 wA = {g0,g1,g2,g3}, wB = {g4,g5,g6,g7};
    *(float4*)&h2[((size_t)node<<3)]     = wA;
    *(float4*)&h2[((size_t)node<<3) + 4] = wB;
    float4 sA = *(const float4*)as2, sB = *(const float4*)(as2+4);
    float4 dA = *(const float4*)ad2, dB = *(const float4*)(ad2+4);
    al2[node] = g0*sA.x+g1*sA.y+g2*sA.z+g3*sA.w+g4*sB.x+g5*sB.y+g6*sB.z+g7*sB.w;
    ar2[node] = g0*dA.x+g1*dA.y+g2*dA.z+g3*dA.w+g4*dB.x+g5*dB.y+g6*dB.z+g7*dB.w;
  }
}

// ---- layer-2 GAT, edge-parallel: lane = one CSR edge; segmented wave scan ----
__global__ __launch_bounds__(256) void k_gat2e(const int2* __restrict__ csr_sd,
    const float* __restrict__ al, const float* __restrict__ ar,
    const unsigned* __restrict__ almax, const float* __restrict__ h2,
    float* __restrict__ nacc, float* __restrict__ nden, int Etot){
  int e = blockIdx.x*256 + threadIdx.x;
  int lane = threadIdx.x & 63;
  bool ok = e < Etot;
  int2 sd = ok ? csr_sd[e] : make_int2(0, -1);
  int s = sd.x, d = sd.y;
  float w = 0.f;
  if (ok){
    float ardv = ar[d];
    float v = al[s] + ardv; v = v > 0.f ? v : SLOPE*v;
    float ub = fdec(almax[0]) + ardv; ub = ub > 0.f ? ub : SLOPE*ub;
    w = __expf(v - ub);
  }
  float4 ha = {0,0,0,0}, hb = {0,0,0,0};
  if (ok){
    ha = *(const float4*)&h2[((size_t)s<<3)];
    hb = *(const float4*)&h2[((size_t)s<<3) + 4];
  }
  float a0 = w*ha.x, a1 = w*ha.y, a2 = w*ha.z, a3 = w*ha.w;
  float a4 = w*hb.x, a5 = w*hb.y, a6 = w*hb.z, a7 = w*hb.w;
  float den = w;
  #pragma unroll
  for (int off = 1; off < 64; off <<= 1){
    int du = __shfl_up(d, off);
    bool add = (lane >= off) && (du == d);
    float t;
    t = __shfl_up(a0, off); if (add) a0 += t;
    t = __shfl_up(a1, off); if (add) a1 += t;
    t = __shfl_up(a2, off); if (add) a2 += t;
    t = __shfl_up(a3, off); if (add) a3 += t;
    t = __shfl_up(a4, off); if (add) a4 += t;
    t = __shfl_up(a5, off); if (add) a5 += t;
    t = __shfl_up(a6, off); if (add) a6 += t;
    t = __shfl_up(a7, off); if (add) a7 += t;
    t = __shfl_up(den, off); if (add) den += t;
  }
  int dn = __shfl_down(d, 1);
  bool tail = (lane == 63) || (dn != d);
  if (tail && d >= 0){
    float* np = nacc + ((size_t)d<<3);
    atomicAdd(np+0, a0); atomicAdd(np+1, a1);
    atomicAdd(np+2, a2); atomicAdd(np+3, a3);
    atomicAdd(np+4, a4); atomicAdd(np+5, a5);
    atomicAdd(np+6, a6); atomicAdd(np+7, a7);
    atomicAdd(&nden[d], den);
  }
}

// ---- finalize layer 2 + pool scatter ----
__global__ __launch_bounds__(256) void k_fin2(const float* __restrict__ nacc,
    const float* __restrict__ nden, const float* __restrict__ b2,
    const int* __restrict__ batch, float* __restrict__ pooled,
    float* __restrict__ cnt, int n){
  int t = blockIdx.x*256 + threadIdx.x;
  int node = t >> 3, j = t & 7;
  if (node >= n) return;
  float o = nacc[t] / (nden[node] + 1e-16f) + b2[j];
  int g = batch[node];
  atomicAdd(&pooled[g*C2N + j], o);
  if (j == 0) atomicAdd(&cnt[g], 1.f);
}

// ---- mean + log_softmax ----
__global__ __launch_bounds__(256) void k_final(const float* __restrict__ pooled,
    const float* __restrict__ cnt, float* __restrict__ out, int G){
  int g = blockIdx.x*blockDim.x + threadIdx.x;
  if (g >= G) return;
  float c = cnt[g]; c = c > 1.f ? c : 1.f;
  float p[8]; float mx = -1e30f;
  #pragma unroll
  for (int j = 0; j < 8; ++j){ p[j] = pooled[g*8+j] / c; mx = fmaxf(mx, p[j]); }
  float s = 0.f;
  #pragma unroll
  for (int j = 0; j < 8; ++j) s += expf(p[j]-mx);
  float lse = mx + logf(s);
  #pragma unroll
  for (int j = 0; j < 8; ++j) out[g*8+j] = p[j] - lse;
}

extern "C" void kernel_launch(void* const* d_in, const int* in_sizes, int n_in,
                              void* d_out, int out_size, void* d_ws, size_t ws_size,
                              hipStream_t stream){
  const float* x    = (const float*)d_in[0];
  const float* gam  = (const float*)d_in[1];
  const float* bet  = (const float*)d_in[2];
  const float* W1   = (const float*)d_in[3];
  const float* as1  = (const float*)d_in[4];
  const float* ad1  = (const float*)d_in[5];
  const float* b1   = (const float*)d_in[6];
  const float* W2   = (const float*)d_in[7];
  const float* as2  = (const float*)d_in[8];
  const float* ad2  = (const float*)d_in[9];
  const float* b2   = (const float*)d_in[10];
  const int*   ei   = (const int*)d_in[11];
  const int*   batch= (const int*)d_in[12];

  int N = in_sizes[0] / F1;
  int E = in_sizes[11] / 2;
  int G = out_size / C2N;
  int Etot = E + N;
  int nb = (N + 1023) / 1024;

  char* base = (char*)d_ws;
  auto alloc = [&](size_t bytes)->char*{
    char* p = base; base += (bytes + 15) & ~15ull; return p;
  };

  // ---- region A: zeroed every launch ----
  char* A0 = base;
  float*    sum     = (float*)alloc(128*4);
  float*    sumsq   = (float*)alloc(128*4);
  int*      deg     = (int*)alloc((size_t)N*4);
  float*    pooled  = (float*)alloc((size_t)G*C2N*4);
  float*    cnt     = (float*)alloc((size_t)G*4);
  unsigned* almax1u = (unsigned*)alloc(16);
  unsigned* almax2u = (unsigned*)alloc(16);
  float*    nacc    = (float*)alloc((size_t)N*C2N*4);
  float*    nden    = (float*)alloc((size_t)N*4);
  size_t Abytes = (size_t)(base - A0);
  // ---- rest ----
  int2*    csr_sd  = (int2*)alloc((size_t)Etot*8);
  float*   ab      = (float*)alloc(256*4);
  int*     rowptr  = (int*)alloc(((size_t)N+4)*4);
  int*     cursor  = (int*)alloc((size_t)N*4);
  int*     bsum    = (int*)alloc((size_t)nb*4);
  __half*  h1      = (__half*)alloc((size_t)N*F1*2);
  float*   al1     = (float*)alloc((size_t)N*4*4);
  float*   ar1     = (float*)alloc((size_t)N*4*4);
  float*   h2      = (float*)alloc((size_t)N*C2N*4);
  float*   al2     = (float*)alloc((size_t)N*4);
  float*   ar2     = (float*)alloc((size_t)N*4);

  hipMemsetAsync(A0, 0, Abytes, stream);

  k_bn_deg<<<512 + (E + 255)/256, 256, 0, stream>>>(x, sum, sumsq, N, ei, deg, E);
  k_bn_final<<<1, 128, 0, stream>>>(sum, sumsq, gam, bet, ab, N);
  k_scan_a<<<nb, 256, 0, stream>>>(deg, rowptr, bsum, N);
  k_scan_c<<<nb, 256, 0, stream>>>(rowptr, cursor, bsum, N);
  k_fill<<<(Etot + 255)/256, 256, 0, stream>>>(ei, cursor, csr_sd, E, Etot);
  k_gemm1<<<(N + 7)/8, 128, 0, stream>>>(x, ab, W1, as1, ad1, h1, al1, ar1, N);
  k_colmax<<<128, 256, 0, stream>>>(al1, almax1u, N*4, 4);
  k_gat1<<<(N + 3)/4, 256, 0, stream>>>(rowptr, csr_sd, al1, ar1, almax1u, h1, b1,
                                        W2, as2, ad2, h2, al2, ar2, N);
  k_colmax<<<64, 256, 0, stream>>>(al2, almax2u, N, 1);
  k_gat2e<<<(Etot + 255)/256, 256, 0, stream>>>(csr_sd, al2, ar2, almax2u, h2, nacc, nden, Etot);
  k_fin2<<<((N*C2N) + 255)/256, 256, 0, stream>>>(nacc, nden, b2, batch, pooled, cnt, N);
  k_final<<<(G + 255)/256, 256, 0, stream>>>(pooled, cnt, (float*)d_out, G);
}

// Round 12
// 322.851 us; speedup vs baseline: 1.4217x; 1.0866x over previous
//
#include <hip/hip_runtime.h>
#include <hip/hip_fp16.h>
#include <math.h>

#define F1 128
#define C2N 8
#define SLOPE 0.2f
#define EPSBN 1e-5f

__device__ __forceinline__ unsigned fenc(float f){
  unsigned u = __float_as_uint(f);
  return (u & 0x80000000u) ? ~u : (u | 0x80000000u);
}
__device__ __forceinline__ float fdec(unsigned u){
  return (u & 0x80000000u) ? __uint_as_float(u & 0x7FFFFFFFu) : __uint_as_float(~u);
}
__device__ __forceinline__ float2 h2f2(unsigned u){
  __half2 h = *(__half2*)&u;
  return __half22float2(h);
}

// ---- fused BatchNorm stats + dst-degree histogram (independent passes) ----
__global__ __launch_bounds__(256) void k_bn_deg(const float* __restrict__ x,
    float* __restrict__ sum, float* __restrict__ sumsq, int n,
    const int* __restrict__ ei, int* __restrict__ deg, int E){
  int bid = blockIdx.x;
  if (bid < 512){
    int f = threadIdx.x & 127;
    int half = threadIdx.x >> 7;
    float s = 0.f, ss = 0.f;
    for (int r = bid*2 + half; r < n; r += 1024){
      float v = x[(size_t)r*F1 + f];
      s += v; ss += v*v;
    }
    atomicAdd(&sum[f], s);
    atomicAdd(&sumsq[f], ss);
  } else {
    int e = (bid - 512)*256 + threadIdx.x;
    if (e < E) atomicAdd(&deg[ei[E + e]], 1);
  }
}

__global__ __launch_bounds__(128) void k_bn_final(const float* __restrict__ sum,
    const float* __restrict__ sumsq, const float* __restrict__ gamma,
    const float* __restrict__ beta, float* __restrict__ ab, int n){
  int f = threadIdx.x;
  float inv_n = 1.f / (float)n;
  float mean = sum[f] * inv_n;
  float var  = sumsq[f] * inv_n - mean*mean;
  float inv  = rsqrtf(var + EPSBN);
  float a = inv * gamma[f];
  ab[f]      = a;
  ab[F1 + f] = beta[f] - mean*a;
}

// ---- fused: normalize + x@W1 + al1/ar1 (blocks < nbG)  ||  CSR fill (rest) ----
__global__ __launch_bounds__(128) void k_gemm1_fill(const float* __restrict__ x,
    const float* __restrict__ ab, const float* __restrict__ W1,
    const float* __restrict__ asrc, const float* __restrict__ adst,
    __half* __restrict__ h1, float* __restrict__ al, float* __restrict__ ar, int n,
    const int* __restrict__ ei, int* __restrict__ cursor,
    int2* __restrict__ csr_sd, int E, int Etot, int nbG){
  if ((int)blockIdx.x >= nbG){
    int e = ((int)blockIdx.x - nbG)*128 + threadIdx.x;
    if (e < Etot){
      int s = (e < E) ? ei[e]     : (e - E);
      int d = (e < E) ? ei[E + e] : (e - E);
      int pos = atomicAdd(&cursor[d], 1);
      csr_sd[pos] = make_int2(s, d);
    }
    return;
  }
  const int j  = threadIdx.x;
  const int r0 = blockIdx.x * 8;
  __shared__ float xs[8][F1];
  float A = ab[j], B = ab[F1 + j];
  int nr = n - r0; if (nr > 8) nr = 8;
  for (int rr = 0; rr < nr; ++rr)
    xs[rr][j] = x[(size_t)(r0+rr)*F1 + j] * A + B;
  __syncthreads();
  float acc[8] = {0,0,0,0,0,0,0,0};
  for (int k = 0; k < F1; ++k){
    float w = W1[k*F1 + j];
    #pragma unroll
    for (int rr = 0; rr < 8; ++rr) acc[rr] += xs[rr][k] * w;
  }
  float as = asrc[j], ad = adst[j];
  for (int rr = 0; rr < nr; ++rr){
    float hv = acc[rr];
    h1[(size_t)(r0+rr)*F1 + j] = __float2half(hv);
    float vs = hv*as, vd = hv*ad;
    #pragma unroll
    for (int mk = 1; mk < 32; mk <<= 1){
      vs += __shfl_xor(vs, mk);
      vd += __shfl_xor(vd, mk);
    }
    if ((j & 31) == 0){
      al[(r0+rr)*4 + (j>>5)] = vs;
      ar[(r0+rr)*4 + (j>>5)] = vd;
    }
  }
}

// ---- global column max of v[total] with h = i & (H-1), H power of 2 ----
__global__ __launch_bounds__(256) void k_colmax(const float* __restrict__ v,
    unsigned* __restrict__ out, int total, int H){
  int tid = blockIdx.x*256 + threadIdx.x;
  int stride = gridDim.x*256;
  float mx = -1e30f;
  for (int i = tid; i < total; i += stride)
    mx = fmaxf(mx, v[i]);
  for (int m = H; m < 64; m <<= 1)
    mx = fmaxf(mx, __shfl_xor(mx, m));
  int lane = threadIdx.x & 63;
  if (lane < H) atomicMax(&out[lane], fenc(mx));
}

// ---- scan A: degrees+1 (self-loop), local exclusive scan + block sum ----
__global__ __launch_bounds__(256) void k_scan_a(const int* __restrict__ deg,
    int* __restrict__ rowptr, int* __restrict__ bsum, int n){
  int t = threadIdx.x;
  int base = blockIdx.x*1024 + t*4;
  int4 v = {0,0,0,0};
  if (base + 3 < n){
    v = *(const int4*)&deg[base];
    v.x += 1; v.y += 1; v.z += 1; v.w += 1;
  } else {
    if (base   < n) v.x = deg[base]   + 1;
    if (base+1 < n) v.y = deg[base+1] + 1;
    if (base+2 < n) v.z = deg[base+2] + 1;
    if (base+3 < n) v.w = deg[base+3] + 1;
  }
  int s = v.x + v.y + v.z + v.w;
  __shared__ int ls[256];
  ls[t] = s; __syncthreads();
  for (int off = 1; off < 256; off <<= 1){
    int u = (t >= off) ? ls[t-off] : 0;
    __syncthreads();
    ls[t] += u;
    __syncthreads();
  }
  int ex = ls[t] - s;
  if (t == 255) bsum[blockIdx.x] = ls[255];
  int4 w;
  w.x = ex;
  w.y = ex + v.x;
  w.z = w.y + v.y;
  w.w = w.z + v.z;
  if (base + 3 < n) *(int4*)&rowptr[base] = w;
  else {
    if (base   < n) rowptr[base]   = w.x;
    if (base+1 < n) rowptr[base+1] = w.y;
    if (base+2 < n) rowptr[base+2] = w.z;
    if (base+3 < n) rowptr[base+3] = w.w;
  }
}

// ---- scan C: add block offsets, mirror cursor, write rowptr[n] ----
__global__ __launch_bounds__(256) void k_scan_c(int* __restrict__ rowptr,
    int* __restrict__ cursor, const int* __restrict__ bsum, int n){
  int t = threadIdx.x;
  __shared__ int s_boff;
  if (t < 64){
    int b = blockIdx.x;
    int val = 0;
    for (int i = t; i < b; i += 64) val += bsum[i];
    #pragma unroll
    for (int m = 1; m < 64; m <<= 1) val += __shfl_xor(val, m);
    if (t == 0) s_boff = val;
  }
  __syncthreads();
  int boff = s_boff;
  if (t == 0 && blockIdx.x == gridDim.x - 1)
    rowptr[n] = boff + bsum[blockIdx.x];
  int base = blockIdx.x*1024 + t*4;
  if (base + 3 < n){
    int4 v = *(int4*)&rowptr[base];
    v.x += boff; v.y += boff; v.z += boff; v.w += boff;
    *(int4*)&rowptr[base] = v;
    *(int4*)&cursor[base] = v;
  } else {
    for (int k = 0; k < 4; ++k)
      if (base + k < n){
        int v = rowptr[base+k] + boff;
        rowptr[base+k] = v; cursor[base+k] = v;
      }
  }
}

// ---- layer-1 GAT + fused x1@W2: wave/node; lane = edge-slot(4) x slice(16) ----
// w2s lane-major layout: w2s[(kk*2+jj)*64 + es*16 + fs] = W2[(fs*8+kk)*8 + es*2+jj]
// -> conflict-free ds_read (64 consecutive floats per (kk,jj)); each es-group
//    computes only its 2 output columns.
__global__ __launch_bounds__(256) void k_gat1(const int* __restrict__ rowptr,
    const int2* __restrict__ csr_sd, const float* __restrict__ al,
    const float* __restrict__ ar, const unsigned* __restrict__ almax,
    const __half* __restrict__ h1, const float* __restrict__ b1,
    const float* __restrict__ W2, const float* __restrict__ as2,
    const float* __restrict__ ad2, float* __restrict__ h2,
    float* __restrict__ al2, float* __restrict__ ar2, int n){
  __shared__ float w2s[1024];
  for (int a = threadIdx.x; a < 1024; a += 256){
    int fs = a & 15;
    int es = (a >> 4) & 3;
    int r  = a >> 6;
    int kk = r >> 1;
    int jj = r & 1;
    w2s[a] = W2[(fs*8 + kk)*C2N + es*2 + jj];
  }
  __syncthreads();
  int node = blockIdx.x*4 + (threadIdx.x >> 6);
  if (node >= n) return;
  int lane = threadIdx.x & 63;
  int es = lane >> 4;          // edge slot 0..3 (also output-column pair)
  int fs = lane & 15;          // 8-fp16 feature slice
  int h  = fs >> 2;            // head
  int f0 = fs << 3;            // feature offset
  int beg = rowptr[node], end = rowptr[node+1];
  float ard = ar[node*4 + h];
  float ub = fdec(almax[h]) + ard;
  ub = ub > 0.f ? ub : SLOPE*ub;
  float a0=0.f,a1=0.f,a2=0.f,a3=0.f,a4=0.f,a5=0.f,a6=0.f,a7=0.f,den=0.f;
  for (int c = beg; c < end; c += 4){
    int idx = c + es;
    bool ok = idx < end;
    int s = csr_sd[ok ? idx : end-1].x;
    float alv = al[s*4 + h];
    float v = alv + ard; v = v > 0.f ? v : SLOPE*v;
    float wv = __expf(v - ub);
    wv = ok ? wv : 0.f;
    den += wv;
    uint4 hv = *(const uint4*)&h1[((size_t)s<<7) + f0];
    float2 p0 = h2f2(hv.x), p1 = h2f2(hv.y), p2 = h2f2(hv.z), p3 = h2f2(hv.w);
    a0 += wv*p0.x; a1 += wv*p0.y; a2 += wv*p1.x; a3 += wv*p1.y;
    a4 += wv*p2.x; a5 += wv*p2.y; a6 += wv*p3.x; a7 += wv*p3.y;
  }
  // reduce over the 4 edge-slot groups (lane bits 4,5) -> all lanes get sums
  #define RED2(X) { X += __shfl_xor(X,16); X += __shfl_xor(X,32); }
  RED2(a0) RED2(a1) RED2(a2) RED2(a3) RED2(a4) RED2(a5) RED2(a6) RED2(a7) RED2(den)
  // x1 row (f32, in-register), ELU
  float inv = 1.f / (den + 1e-16f);
  float4 bA = *(const float4*)&b1[f0];
  float4 bB = *(const float4*)&b1[f0+4];
  float o0 = a0*inv + bA.x, o1 = a1*inv + bA.y;
  float o2 = a2*inv + bA.z, o3 = a3*inv + bA.w;
  float o4 = a4*inv + bB.x, o5 = a5*inv + bB.y;
  float o6 = a6*inv + bB.z, o7 = a7*inv + bB.w;
  o0 = o0 > 0.f ? o0 : expm1f(o0);
  o1 = o1 > 0.f ? o1 : expm1f(o1);
  o2 = o2 > 0.f ? o2 : expm1f(o2);
  o3 = o3 > 0.f ? o3 : expm1f(o3);
  o4 = o4 > 0.f ? o4 : expm1f(o4);
  o5 = o5 > 0.f ? o5 : expm1f(o5);
  o6 = o6 > 0.f ? o6 : expm1f(o6);
  o7 = o7 > 0.f ? o7 : expm1f(o7);
  // fused gemm2, split by output-column pair: this es-group computes j=2es,2es+1
  const float* wG = w2s + es*16 + fs;
  float gA = 0.f, gB = 0.f;
  gA += o0*wG[0];   gB += o0*wG[64];
  gA += o1*wG[128]; gB += o1*wG[192];
  gA += o2*wG[256]; gB += o2*wG[320];
  gA += o3*wG[384]; gB += o3*wG[448];
  gA += o4*wG[512]; gB += o4*wG[576];
  gA += o5*wG[640]; gB += o5*wG[704];
  gA += o6*wG[768]; gB += o6*wG[832];
  gA += o7*wG[896]; gB += o7*wG[960];
  // reduce over the 16 slices (lane bits 0..3)
  #define RED4(X) { X += __shfl_xor(X,1); X += __shfl_xor(X,2); \
                    X += __shfl_xor(X,4); X += __shfl_xor(X,8); }
  RED4(gA) RED4(gB)
  #undef RED4
  // al2/ar2 partials per es-pair, then reduce across es
  float pal = gA*as2[es*2] + gB*as2[es*2+1];
  float par = gA*ad2[es*2] + gB*ad2[es*2+1];
  RED2(pal) RED2(par)
  #undef RED2
  if (fs == 0){
    float2 hw = {gA, gB};
    *(float2*)&h2[((size_t)node<<3) + es*2] = hw;
  }
  if (lane == 0){
    al2[node] = pal;
    ar2[node] = par;
  }
}

// ---- layer-2 GAT, edge-parallel: lane = one CSR edge; segmented wave scan ----
__global__ __launch_bounds__(256) void k_gat2e(const int2* __restrict__ csr_sd,
    const float* __restrict__ al, const float* __restrict__ ar,
    const unsigned* __restrict__ almax, const float* __restrict__ h2,
    float* __restrict__ nacc, float* __restrict__ nden, int Etot){
  int e = blockIdx.x*256 + threadIdx.x;
  int lane = threadIdx.x & 63;
  bool ok = e < Etot;
  int2 sd = ok ? csr_sd[e] : make_int2(0, -1);
  int s = sd.x, d = sd.y;
  float w = 0.f;
  if (ok){
    float ardv = ar[d];
    float v = al[s] + ardv; v = v > 0.f ? v : SLOPE*v;
    float ub = fdec(almax[0]) + ardv; ub = ub > 0.f ? ub : SLOPE*ub;
    w = __expf(v - ub);
  }
  float4 ha = {0,0,0,0}, hb = {0,0,0,0};
  if (ok){
    ha = *(const float4*)&h2[((size_t)s<<3)];
    hb = *(const float4*)&h2[((size_t)s<<3) + 4];
  }
  float a0 = w*ha.x, a1 = w*ha.y, a2 = w*ha.z, a3 = w*ha.w;
  float a4 = w*hb.x, a5 = w*hb.y, a6 = w*hb.z, a7 = w*hb.w;
  float den = w;
  #pragma unroll
  for (int off = 1; off < 64; off <<= 1){
    int du = __shfl_up(d, off);
    bool add = (lane >= off) && (du == d);
    float t;
    t = __shfl_up(a0, off); if (add) a0 += t;
    t = __shfl_up(a1, off); if (add) a1 += t;
    t = __shfl_up(a2, off); if (add) a2 += t;
    t = __shfl_up(a3, off); if (add) a3 += t;
    t = __shfl_up(a4, off); if (add) a4 += t;
    t = __shfl_up(a5, off); if (add) a5 += t;
    t = __shfl_up(a6, off); if (add) a6 += t;
    t = __shfl_up(a7, off); if (add) a7 += t;
    t = __shfl_up(den, off); if (add) den += t;
  }
  int dn = __shfl_down(d, 1);
  bool tail = (lane == 63) || (dn != d);
  if (tail && d >= 0){
    float* np = nacc + ((size_t)d<<3);
    atomicAdd(np+0, a0); atomicAdd(np+1, a1);
    atomicAdd(np+2, a2); atomicAdd(np+3, a3);
    atomicAdd(np+4, a4); atomicAdd(np+5, a5);
    atomicAdd(np+6, a6); atomicAdd(np+7, a7);
    atomicAdd(&nden[d], den);
  }
}

// ---- finalize layer 2 + pool scatter ----
__global__ __launch_bounds__(256) void k_fin2(const float* __restrict__ nacc,
    const float* __restrict__ nden, const float* __restrict__ b2,
    const int* __restrict__ batch, float* __restrict__ pooled,
    float* __restrict__ cnt, int n){
  int t = blockIdx.x*256 + threadIdx.x;
  int node = t >> 3, j = t & 7;
  if (node >= n) return;
  float o = nacc[t] / (nden[node] + 1e-16f) + b2[j];
  int g = batch[node];
  atomicAdd(&pooled[g*C2N + j], o);
  if (j == 0) atomicAdd(&cnt[g], 1.f);
}

// ---- mean + log_softmax ----
__global__ __launch_bounds__(256) void k_final(const float* __restrict__ pooled,
    const float* __restrict__ cnt, float* __restrict__ out, int G){
  int g = blockIdx.x*blockDim.x + threadIdx.x;
  if (g >= G) return;
  float c = cnt[g]; c = c > 1.f ? c : 1.f;
  float p[8]; float mx = -1e30f;
  #pragma unroll
  for (int j = 0; j < 8; ++j){ p[j] = pooled[g*8+j] / c; mx = fmaxf(mx, p[j]); }
  float s = 0.f;
  #pragma unroll
  for (int j = 0; j < 8; ++j) s += expf(p[j]-mx);
  float lse = mx + logf(s);
  #pragma unroll
  for (int j = 0; j < 8; ++j) out[g*8+j] = p[j] - lse;
}

extern "C" void kernel_launch(void* const* d_in, const int* in_sizes, int n_in,
                              void* d_out, int out_size, void* d_ws, size_t ws_size,
                              hipStream_t stream){
  const float* x    = (const float*)d_in[0];
  const float* gam  = (const float*)d_in[1];
  const float* bet  = (const float*)d_in[2];
  const float* W1   = (const float*)d_in[3];
  const float* as1  = (const float*)d_in[4];
  const float* ad1  = (const float*)d_in[5];
  const float* b1   = (const float*)d_in[6];
  const float* W2   = (const float*)d_in[7];
  const float* as2  = (const float*)d_in[8];
  const float* ad2  = (const float*)d_in[9];
  const float* b2   = (const float*)d_in[10];
  const int*   ei   = (const int*)d_in[11];
  const int*   batch= (const int*)d_in[12];

  int N = in_sizes[0] / F1;
  int E = in_sizes[11] / 2;
  int G = out_size / C2N;
  int Etot = E + N;
  int nb = (N + 1023) / 1024;
  int nbG = (N + 7) / 8;
  int nbF = (Etot + 127) / 128;

  char* base = (char*)d_ws;
  auto alloc = [&](size_t bytes)->char*{
    char* p = base; base += (bytes + 15) & ~15ull; return p;
  };

  // ---- region A: zeroed every launch ----
  char* A0 = base;
  float*    sum     = (float*)alloc(128*4);
  float*    sumsq   = (float*)alloc(128*4);
  int*      deg     = (int*)alloc((size_t)N*4);
  float*    pooled  = (float*)alloc((size_t)G*C2N*4);
  float*    cnt     = (float*)alloc((size_t)G*4);
  unsigned* almax1u = (unsigned*)alloc(16);
  unsigned* almax2u = (unsigned*)alloc(16);
  float*    nacc    = (float*)alloc((size_t)N*C2N*4);
  float*    nden    = (float*)alloc((size_t)N*4);
  size_t Abytes = (size_t)(base - A0);
  // ---- rest ----
  int2*    csr_sd  = (int2*)alloc((size_t)Etot*8);
  float*   ab      = (float*)alloc(256*4);
  int*     rowptr  = (int*)alloc(((size_t)N+4)*4);
  int*     cursor  = (int*)alloc((size_t)N*4);
  int*     bsum    = (int*)alloc((size_t)nb*4);
  __half*  h1      = (__half*)alloc((size_t)N*F1*2);
  float*   al1     = (float*)alloc((size_t)N*4*4);
  float*   ar1     = (float*)alloc((size_t)N*4*4);
  float*   h2      = (float*)alloc((size_t)N*C2N*4);
  float*   al2     = (float*)alloc((size_t)N*4);
  float*   ar2     = (float*)alloc((size_t)N*4);

  hipMemsetAsync(A0, 0, Abytes, stream);

  k_bn_deg<<<512 + (E + 255)/256, 256, 0, stream>>>(x, sum, sumsq, N, ei, deg, E);
  k_bn_final<<<1, 128, 0, stream>>>(sum, sumsq, gam, bet, ab, N);
  k_scan_a<<<nb, 256, 0, stream>>>(deg, rowptr, bsum, N);
  k_scan_c<<<nb, 256, 0, stream>>>(rowptr, cursor, bsum, N);
  k_gemm1_fill<<<nbG + nbF, 128, 0, stream>>>(x, ab, W1, as1, ad1, h1, al1, ar1, N,
                                              ei, cursor, csr_sd, E, Etot, nbG);
  k_colmax<<<128, 256, 0, stream>>>(al1, almax1u, N*4, 4);
  k_gat1<<<(N + 3)/4, 256, 0, stream>>>(rowptr, csr_sd, al1, ar1, almax1u, h1, b1,
                                        W2, as2, ad2, h2, al2, ar2, N);
  k_colmax<<<64, 256, 0, stream>>>(al2, almax2u, N, 1);
  k_gat2e<<<(Etot + 255)/256, 256, 0, stream>>>(csr_sd, al2, ar2, almax2u, h2, nacc, nden, Etot);
  k_fin2<<<((N*C2N) + 255)/256, 256, 0, stream>>>(nacc, nden, b2, batch, pooled, cnt, N);
  k_final<<<(G + 255)/256, 256, 0, stream>>>(pooled, cnt, (float*)d_out, G);
}